// Round 4
// baseline (6555.234 us; speedup 1.0000x reference)
//
#include <hip/hip_runtime.h>
#include <math.h>
#include <stdint.h>

// Problem constants
static constexpr int B_ = 128;
static constexpr int T_ = 64;
static constexpr int E_ = 2048;
static constexpr int H_ = 1024;
static constexpr int R_ = 8;
static constexpr int H3_ = 3 * H_;  // 3072
static constexpr int NB_ = 240;     // persistent grid: 24 n-tiles x 10 groups

typedef unsigned short u16;
typedef __attribute__((ext_vector_type(8))) __bf16 bf16x8;
typedef __attribute__((ext_vector_type(4))) float f32x4;

__device__ __forceinline__ u16 f2bf(float f) {
    uint32_t x = __float_as_uint(f);
    x += 0x7fffu + ((x >> 16) & 1u);      // round-to-nearest-even
    return (u16)(x >> 16);
}
__device__ __forceinline__ float bf2f(u16 u) {
    return __uint_as_float(((uint32_t)u) << 16);
}

// async global->LDS, 16B per lane; LDS dest = wave-uniform base + lane*16
__device__ __forceinline__ void async_cp16(const u16* g, u16* l) {
    auto* g1 = (const __attribute__((address_space(1))) u16*)g;
    auto* l3 = (__attribute__((address_space(3))) u16*)(uintptr_t)l;
    __builtin_amdgcn_global_load_lds((const __attribute__((address_space(1))) void*)g1,
                                     (__attribute__((address_space(3))) void*)l3,
                                     16, 0, 0);
}

// ---------------------------------------------------------------------------
__global__ __launch_bounds__(256) void zero_kernel(float* __restrict__ p, int n) {
    int i = blockIdx.x * 256 + threadIdx.x;
    if (i < n) p[i] = 0.0f;
}

// fp32 -> bf16 pack: dst[r*cols+c] = bf16(src[r*src_ld + col0 + c])
__global__ __launch_bounds__(256) void conv_bf(
    const float* __restrict__ src, int src_ld, int col0, int cols,
    u16* __restrict__ dst, int total4)
{
    int i4 = blockIdx.x * 256 + threadIdx.x;
    if (i4 >= total4) return;
    int i = i4 * 4;
    int r = i / cols, c = i - r * cols;
    const float4 v = *(const float4*)(src + (size_t)r * src_ld + col0 + c);
    ushort4 o;
    o.x = f2bf(v.x); o.y = f2bf(v.y); o.z = f2bf(v.z); o.w = f2bf(v.w);
    *(ushort4*)(dst + i) = o;
}

// ---------------------------------------------------------------------------
// Phase 1 MFMA GEMM: C[m,n] = bf16( sum_k X[row(m),k]*W[n,k] + bias[n] )
// 128x128 tile, BK=32, 256 thr (4 waves, 2x2 of 64x64), 16x16x32 MFMA.
// ---------------------------------------------------------------------------
__global__ __launch_bounds__(256) void mfma_p1(
    const u16* __restrict__ X, int t0, int tcshift,
    const u16* __restrict__ W, const float* __restrict__ bias,
    u16* __restrict__ C)
{
    __shared__ u16 As[128 * 32];
    __shared__ u16 Bs[128 * 32];
    __shared__ int rowoff[128];
    const int tid = threadIdx.x;
    const int n0 = blockIdx.x * 128;
    const int m0 = blockIdx.y * 128;
    const int tcmask = (1 << tcshift) - 1;
    if (tid < 128) {
        int m = m0 + tid;
        rowoff[tid] = ((m >> tcshift) * T_ + t0 + (m & tcmask)) * E_;
    }
    __syncthreads();

    const int lane = tid & 63;
    const int wm = ((tid >> 6) & 1) * 64;
    const int wn = (tid >> 7) * 64;
    const int fr = lane & 15;            // fragment row (m for A, n for B)
    const int kq = (lane >> 4) * 8;      // k-quad offset
    const int wbase = (tid & 192) * 8;   // wave-uniform LDS chunk base (elems)

    f32x4 acc[4][4] = {};

    for (int k0 = 0; k0 < E_; k0 += 32) {
#pragma unroll
        for (int p = 0; p < 2; ++p) {
            int c = p * 256 + tid;
            int row = c >> 2, kc = (c & 3) * 8;
            async_cp16(X + rowoff[row] + k0 + kc, &As[p * 2048 + wbase]);
            async_cp16(W + (size_t)(n0 + row) * E_ + k0 + kc, &Bs[p * 2048 + wbase]);
        }
        __syncthreads();
        bf16x8 a[4], b[4];
#pragma unroll
        for (int i = 0; i < 4; ++i) {
            a[i] = *(const bf16x8*)&As[(wm + i * 16 + fr) * 32 + kq];
            b[i] = *(const bf16x8*)&Bs[(wn + i * 16 + fr) * 32 + kq];
        }
#pragma unroll
        for (int mt = 0; mt < 4; ++mt)
#pragma unroll
            for (int nt = 0; nt < 4; ++nt)
                acc[mt][nt] = __builtin_amdgcn_mfma_f32_16x16x32_bf16(
                    a[mt], b[nt], acc[mt][nt], 0, 0, 0);
        __syncthreads();
    }

#pragma unroll
    for (int mt = 0; mt < 4; ++mt)
#pragma unroll
        for (int nt = 0; nt < 4; ++nt) {
            int n = n0 + wn + nt * 16 + fr;
            float bs = bias[n];
#pragma unroll
            for (int i = 0; i < 4; ++i) {
                int m = m0 + wm + mt * 16 + (lane >> 4) * 4 + i;
                C[(size_t)m * H3_ + n] = f2bf(acc[mt][nt][i] + bs);
            }
        }
}

// ---------------------------------------------------------------------------
// Persistent recurrence kernel: Tc steps in ONE launch.
// Grid = 240 blocks. Per step:
//   GEMM phase: block (nx, gy) computes its 128x128 tile of G (fp32)
//     gy=0: giS = A[b,adr]@Whsi^T | gy=1: ghS = A[b,spk]@Whs^T
//     gy=2: giA = A[b,spk]@Whai^T | gy=3: ghA = A[b,adr]@Wha^T
//     gy=4..9: ghO = A[b,oth_j]@Who^T (768 rows)
//   grid barrier -> gate phase (4096 chunks of 256 elems over 240 blocks)
//   grid barrier -> next t.
// Barrier: monotonic-epoch counter, agent-scope fences, s_sleep backoff.
// ---------------------------------------------------------------------------
__device__ __forceinline__ void gbar(int* cnt, int target) {
    __syncthreads();
    if (threadIdx.x == 0) {
        __threadfence();   // release: write back this XCD's L2
        __hip_atomic_fetch_add(cnt, 1, __ATOMIC_RELAXED, __HIP_MEMORY_SCOPE_AGENT);
        while (__hip_atomic_load(cnt, __ATOMIC_RELAXED, __HIP_MEMORY_SCOPE_AGENT) < target)
            __builtin_amdgcn_s_sleep(8);
        __threadfence();   // acquire: invalidate stale L1/L2
    }
    __syncthreads();
}

__global__ __launch_bounds__(256) void recur_persist(
    u16* __restrict__ Abf, float* __restrict__ A0, float* __restrict__ A1,
    const int* __restrict__ dig, int t0, int Tc,
    const u16* __restrict__ Whsi, const u16* __restrict__ Whs,
    const u16* __restrict__ Whai, const u16* __restrict__ Wha,
    const u16* __restrict__ Who,
    const u16* __restrict__ GIX, const u16* __restrict__ GIA,
    const u16* __restrict__ GIO,
    const float* __restrict__ ws_bhh, const float* __restrict__ wa_bhh,
    const float* __restrict__ wo_bhh,
    float* __restrict__ G, int* __restrict__ cnt)
{
    __shared__ u16 As[128 * 32];
    __shared__ u16 Bs[128 * 32];
    __shared__ int rowoff[128];
    const int tid = threadIdx.x;
    const int bid = blockIdx.x;
    const int nx = bid % 24, gy = bid / 24;
    const int n0 = nx * 128;

    const u16* W;
    float* Cout;
    if (gy == 0)      { W = Whsi; Cout = G; }
    else if (gy == 1) { W = Whs;  Cout = G + (size_t)128 * H3_; }
    else if (gy == 2) { W = Whai; Cout = G + (size_t)256 * H3_; }
    else if (gy == 3) { W = Wha;  Cout = G + (size_t)384 * H3_; }
    else              { W = Who;  Cout = G + (size_t)(512 + (gy - 4) * 128) * H3_; }

    const int lane = tid & 63;
    const int wm = ((tid >> 6) & 1) * 64;
    const int wn = (tid >> 7) * 64;
    const int fr = lane & 15;
    const int kq = (lane >> 4) * 8;
    const int wbase = (tid & 192) * 8;

    int ep = 0;

    for (int tl = 0; tl < Tc; ++tl) {
        const int t = t0 + tl;
        const float* Aold = ((t & 1) == 0) ? A0 : A1;
        float*       Anew = ((t & 1) == 0) ? A1 : A0;

        // ---- GEMM phase ----
        if (tid < 128) {
            int role, b;
            if (gy < 4) {
                b = tid;
                int spk = dig[(b * T_ + t) * 2 + 0];
                int adr = dig[(b * T_ + t) * 2 + 1];
                role = (gy == 0 || gy == 3) ? adr : spk;
            } else {
                int mo = (gy - 4) * 128 + tid;
                b = mo / 6;
                int j = mo - b * 6;
                int spk = dig[(b * T_ + t) * 2 + 0];
                int adr = dig[(b * T_ + t) * 2 + 1];
                int cc = 0; role = 0;
                for (int r = 0; r < R_; ++r) {
                    if (r != spk && r != adr) {
                        if (cc == j) { role = r; break; }
                        ++cc;
                    }
                }
            }
            rowoff[tid] = (b * R_ + role) * H_;
        }
        __syncthreads();

        f32x4 acc[4][4] = {};
        for (int k0 = 0; k0 < H_; k0 += 32) {
#pragma unroll
            for (int p = 0; p < 2; ++p) {
                int c = p * 256 + tid;
                int row = c >> 2, kc = (c & 3) * 8;
                async_cp16(Abf + rowoff[row] + k0 + kc, &As[p * 2048 + wbase]);
                async_cp16(W + (size_t)(n0 + row) * H_ + k0 + kc, &Bs[p * 2048 + wbase]);
            }
            __syncthreads();
            bf16x8 a[4], b[4];
#pragma unroll
            for (int i = 0; i < 4; ++i) {
                a[i] = *(const bf16x8*)&As[(wm + i * 16 + fr) * 32 + kq];
                b[i] = *(const bf16x8*)&Bs[(wn + i * 16 + fr) * 32 + kq];
            }
#pragma unroll
            for (int mt = 0; mt < 4; ++mt)
#pragma unroll
                for (int nt = 0; nt < 4; ++nt)
                    acc[mt][nt] = __builtin_amdgcn_mfma_f32_16x16x32_bf16(
                        a[mt], b[nt], acc[mt][nt], 0, 0, 0);
            __syncthreads();
        }
#pragma unroll
        for (int mt = 0; mt < 4; ++mt)
#pragma unroll
            for (int nt = 0; nt < 4; ++nt) {
                int n = n0 + wn + nt * 16 + fr;
#pragma unroll
                for (int i = 0; i < 4; ++i) {
                    int m = wm + mt * 16 + (lane >> 4) * 4 + i;
                    Cout[(size_t)m * H3_ + n] = acc[mt][nt][i];
                }
            }

        ++ep; gbar(cnt, NB_ * ep);

        // ---- gate phase: 1024 (b,r) pairs x 4 segs of 256 elems ----
        for (int c = bid; c < 4096; c += NB_) {
            int pair = c >> 2;
            int i = ((c & 3) << 8) | tid;
            int b = pair >> 3, r = pair & 7;
            int spk = dig[(b * T_ + t) * 2 + 0];
            int adr = dig[(b * T_ + t) * 2 + 1];
            const size_t gi_row = (size_t)(b * Tc + tl) * H3_;

            const u16* gi_pre;
            const float* gi_add = nullptr;
            const float* gh;
            const float* bhh;
            if (r == spk) {
                gi_pre = GIX + gi_row;
                gi_add = G + (size_t)b * H3_;
                gh     = G + (size_t)(128 + b) * H3_;
                bhh    = ws_bhh;
            } else if (r == adr) {
                gi_pre = GIA + gi_row;
                gi_add = G + (size_t)(256 + b) * H3_;
                gh     = G + (size_t)(384 + b) * H3_;
                bhh    = wa_bhh;
            } else {
                int oidx = r - (spk < r ? 1 : 0) - (adr < r ? 1 : 0);
                gi_pre = GIO + gi_row;
                gh     = G + (size_t)(512 + b * 6 + oidx) * H3_;
                bhh    = wo_bhh;
            }

            float gir = bf2f(gi_pre[i]);
            float giz = bf2f(gi_pre[H_ + i]);
            float gin = bf2f(gi_pre[2 * H_ + i]);
            if (gi_add) {
                gir += gi_add[i];
                giz += gi_add[H_ + i];
                gin += gi_add[2 * H_ + i];
            }
            float ghr = gh[i]          + bhh[i];
            float ghz = gh[H_ + i]     + bhh[H_ + i];
            float ghn = gh[2 * H_ + i] + bhh[2 * H_ + i];

            float rg = 1.0f / (1.0f + __expf(-(gir + ghr)));
            float zg = 1.0f / (1.0f + __expf(-(giz + ghz)));
            float ng = tanhf(gin + rg * ghn);
            size_t hoff = (size_t)(b * R_ + r) * H_ + i;
            float h = Aold[hoff];
            float o = (1.0f - zg) * ng + zg * h;
            Anew[hoff] = o;
            Abf[hoff]  = f2bf(o);
        }

        ++ep; gbar(cnt, NB_ * ep);
    }
}

// ---------------------------------------------------------------------------
extern "C" void kernel_launch(void* const* d_in, const int* in_sizes, int n_in,
                              void* d_out, int out_size, void* d_ws, size_t ws_size,
                              hipStream_t stream) {
    const float* enc    = (const float*)d_in[0];
    const int*   dig    = (const int*)d_in[1];
    const float* ws_ih  = (const float*)d_in[2];
    const float* ws_hh  = (const float*)d_in[3];
    const float* ws_bih = (const float*)d_in[4];
    const float* ws_bhh = (const float*)d_in[5];
    const float* wa_ih  = (const float*)d_in[6];
    const float* wa_hh  = (const float*)d_in[7];
    const float* wa_bih = (const float*)d_in[8];
    const float* wa_bhh = (const float*)d_in[9];
    const float* wo_ih  = (const float*)d_in[10];
    const float* wo_hh  = (const float*)d_in[11];
    const float* wo_bih = (const float*)d_in[12];
    const float* wo_bhh = (const float*)d_in[13];

    float* A0 = (float*)d_out;                    // (B, R, H) final output

    // ---- workspace layout (bytes) ----
    char* p = (char*)d_ws;
    auto take = [&](size_t bytes) { char* q = p; p += (bytes + 255) & ~(size_t)255; return q; };
    int*   cnt    = (int*)  take(256);
    u16*   enc_bf = (u16*)  take((size_t)B_ * T_ * E_ * 2);          // 33.6 MB
    u16*   W1s    = (u16*)  take((size_t)H3_ * E_ * 2);              // 12.6 MB
    u16*   W1a    = (u16*)  take((size_t)H3_ * E_ * 2);
    u16*   W1o    = (u16*)  take((size_t)H3_ * E_ * 2);
    u16*   Whsi   = (u16*)  take((size_t)H3_ * H_ * 2);              // 6.3 MB
    u16*   Whai   = (u16*)  take((size_t)H3_ * H_ * 2);
    u16*   Whs    = (u16*)  take((size_t)H3_ * H_ * 2);
    u16*   Wha    = (u16*)  take((size_t)H3_ * H_ * 2);
    u16*   Who    = (u16*)  take((size_t)H3_ * H_ * 2);
    u16*   Abf    = (u16*)  take((size_t)B_ * R_ * H_ * 2);          // 2 MB
    float* A1     = (float*)take((size_t)B_ * R_ * H_ * 4);          // 4 MB
    float* G      = (float*)take((size_t)1280 * H3_ * 4);            // 15.7 MB
    size_t fixed = (size_t)(p - (char*)d_ws);

    // chunk size: largest power-of-two Tc <= 64 fitting GI (3 sets, bf16)
    const size_t per_t = (size_t)3 * B_ * H3_ * 2;                   // 2.36 MB/step
    int Tc = 64;
    while (Tc > 1 && fixed + per_t * (size_t)Tc > ws_size) Tc >>= 1;
    int tcshift = 0;
    while ((1 << tcshift) < Tc) ++tcshift;
    const size_t GI_elems = (size_t)B_ * Tc * H3_;
    u16* GIX = (u16*)take(GI_elems * 2);
    u16* GIA = (u16*)take(GI_elems * 2);
    u16* GIO = (u16*)take(GI_elems * 2);

    dim3 blk(256);
    const size_t A_sz = (size_t)B_ * R_ * H_;

    // zero fp32 state (d_out) and bf16 state copy
    zero_kernel<<<dim3((int)((A_sz + 255) / 256)), blk, 0, stream>>>(A0, (int)A_sz);
    zero_kernel<<<dim3((int)((A_sz / 2 + 255) / 256)), blk, 0, stream>>>((float*)Abf, (int)(A_sz / 2));

    // ---- one-time bf16 conversions ----
    {
        int t4;
        t4 = B_ * T_ * E_ / 4;
        conv_bf<<<dim3((t4 + 255) / 256), blk, 0, stream>>>(enc, E_, 0, E_, enc_bf, t4);
        t4 = H3_ * E_ / 4;
        conv_bf<<<dim3((t4 + 255) / 256), blk, 0, stream>>>(ws_ih, E_ + H_, 0, E_, W1s, t4);
        conv_bf<<<dim3((t4 + 255) / 256), blk, 0, stream>>>(wa_ih, E_ + H_, 0, E_, W1a, t4);
        conv_bf<<<dim3((t4 + 255) / 256), blk, 0, stream>>>(wo_ih, E_, 0, E_, W1o, t4);
        t4 = H3_ * H_ / 4;
        conv_bf<<<dim3((t4 + 255) / 256), blk, 0, stream>>>(ws_ih, E_ + H_, E_, H_, Whsi, t4);
        conv_bf<<<dim3((t4 + 255) / 256), blk, 0, stream>>>(wa_ih, E_ + H_, E_, H_, Whai, t4);
        conv_bf<<<dim3((t4 + 255) / 256), blk, 0, stream>>>(ws_hh, H_, 0, H_, Whs, t4);
        conv_bf<<<dim3((t4 + 255) / 256), blk, 0, stream>>>(wa_hh, H_, 0, H_, Wha, t4);
        conv_bf<<<dim3((t4 + 255) / 256), blk, 0, stream>>>(wo_hh, H_, 0, H_, Who, t4);
    }

    for (int t0 = 0; t0 < T_; t0 += Tc) {
        // Phase 1 (chunk): input-side gate contributions, bf16 MFMA.
        dim3 g1(H3_ / 128, (B_ * Tc) / 128);
        mfma_p1<<<g1, blk, 0, stream>>>(enc_bf, t0, tcshift, W1s, ws_bih, GIX);
        mfma_p1<<<g1, blk, 0, stream>>>(enc_bf, t0, tcshift, W1a, wa_bih, GIA);
        mfma_p1<<<g1, blk, 0, stream>>>(enc_bf, t0, tcshift, W1o, wo_bih, GIO);

        // zero barrier counter, then run Tc steps in one persistent launch
        zero_kernel<<<dim3(1), blk, 0, stream>>>((float*)cnt, 64);
        recur_persist<<<dim3(NB_), blk, 0, stream>>>(
            Abf, A0, A1, dig, t0, Tc,
            Whsi, Whs, Whai, Wha, Who, GIX, GIA, GIO,
            ws_bhh, wa_bhh, wo_bhh, G, cnt);
    }
    // T_ = 64 total steps (even): final state lands in A0 == d_out.
}

// Round 5
// 5254.966 us; speedup vs baseline: 1.2474x; 1.2474x over previous
//
#include <hip/hip_runtime.h>
#include <math.h>
#include <stdint.h>

// Problem constants
static constexpr int B_ = 128;
static constexpr int T_ = 64;
static constexpr int E_ = 2048;
static constexpr int H_ = 1024;
static constexpr int R_ = 8;
static constexpr int H3_ = 3 * H_;  // 3072

typedef unsigned short u16;
typedef __attribute__((ext_vector_type(8))) __bf16 bf16x8;
typedef __attribute__((ext_vector_type(4))) float f32x4;

__device__ __forceinline__ u16 f2bf(float f) {
    uint32_t x = __float_as_uint(f);
    x += 0x7fffu + ((x >> 16) & 1u);      // round-to-nearest-even
    return (u16)(x >> 16);
}
__device__ __forceinline__ float bf2f(u16 u) {
    return __uint_as_float(((uint32_t)u) << 16);
}

// async global->LDS, 16B per lane; LDS dest = wave-uniform base + lane*16
__device__ __forceinline__ void async_cp16(const u16* g, u16* l) {
    auto* g1 = (const __attribute__((address_space(1))) u16*)g;
    auto* l3 = (__attribute__((address_space(3))) u16*)(uintptr_t)l;
    __builtin_amdgcn_global_load_lds((const __attribute__((address_space(1))) void*)g1,
                                     (__attribute__((address_space(3))) void*)l3,
                                     16, 0, 0);
}

// ---------------------------------------------------------------------------
__global__ __launch_bounds__(256) void zero_kernel(float* __restrict__ p, int n) {
    int i = blockIdx.x * 256 + threadIdx.x;
    if (i < n) p[i] = 0.0f;
}

// fp32 -> bf16 pack: dst[r*cols+c] = bf16(src[r*src_ld + col0 + c])
__global__ __launch_bounds__(256) void conv_bf(
    const float* __restrict__ src, int src_ld, int col0, int cols,
    u16* __restrict__ dst, int total4)
{
    int i4 = blockIdx.x * 256 + threadIdx.x;
    if (i4 >= total4) return;
    int i = i4 * 4;
    int r = i / cols, c = i - r * cols;
    const float4 v = *(const float4*)(src + (size_t)r * src_ld + col0 + c);
    ushort4 o;
    o.x = f2bf(v.x); o.y = f2bf(v.y); o.z = f2bf(v.z); o.w = f2bf(v.w);
    *(ushort4*)(dst + i) = o;
}

// ---------------------------------------------------------------------------
// Phase 1 MFMA GEMM: C[m,n] = bf16( sum_k X[row(m),k]*W[n,k] + bias[n] )
// 128x128 tile, BK=32, 256 thr (4 waves, 2x2 of 64x64), 16x16x32 MFMA.
// ---------------------------------------------------------------------------
__global__ __launch_bounds__(256) void mfma_p1(
    const u16* __restrict__ X, int t0, int tcshift,
    const u16* __restrict__ W, const float* __restrict__ bias,
    u16* __restrict__ C)
{
    __shared__ u16 As[128 * 32];
    __shared__ u16 Bs[128 * 32];
    __shared__ int rowoff[128];
    const int tid = threadIdx.x;
    const int n0 = blockIdx.x * 128;
    const int m0 = blockIdx.y * 128;
    const int tcmask = (1 << tcshift) - 1;
    if (tid < 128) {
        int m = m0 + tid;
        rowoff[tid] = ((m >> tcshift) * T_ + t0 + (m & tcmask)) * E_;
    }
    __syncthreads();

    const int lane = tid & 63;
    const int wm = ((tid >> 6) & 1) * 64;
    const int wn = (tid >> 7) * 64;
    const int fr = lane & 15;
    const int kq = (lane >> 4) * 8;
    const int wbase = (tid & 192) * 8;

    f32x4 acc[4][4] = {};

    for (int k0 = 0; k0 < E_; k0 += 32) {
#pragma unroll
        for (int p = 0; p < 2; ++p) {
            int c = p * 256 + tid;
            int row = c >> 2, kc = (c & 3) * 8;
            async_cp16(X + rowoff[row] + k0 + kc, &As[p * 2048 + wbase]);
            async_cp16(W + (size_t)(n0 + row) * E_ + k0 + kc, &Bs[p * 2048 + wbase]);
        }
        __syncthreads();
        bf16x8 a[4], b[4];
#pragma unroll
        for (int i = 0; i < 4; ++i) {
            a[i] = *(const bf16x8*)&As[(wm + i * 16 + fr) * 32 + kq];
            b[i] = *(const bf16x8*)&Bs[(wn + i * 16 + fr) * 32 + kq];
        }
#pragma unroll
        for (int mt = 0; mt < 4; ++mt)
#pragma unroll
            for (int nt = 0; nt < 4; ++nt)
                acc[mt][nt] = __builtin_amdgcn_mfma_f32_16x16x32_bf16(
                    a[mt], b[nt], acc[mt][nt], 0, 0, 0);
        __syncthreads();
    }

#pragma unroll
    for (int mt = 0; mt < 4; ++mt)
#pragma unroll
        for (int nt = 0; nt < 4; ++nt) {
            int n = n0 + wn + nt * 16 + fr;
            float bs = bias[n];
#pragma unroll
            for (int i = 0; i < 4; ++i) {
                int m = m0 + wm + mt * 16 + (lane >> 4) * 4 + i;
                C[(size_t)m * H3_ + n] = f2bf(acc[mt][nt][i] + bs);
            }
        }
}

// ---------------------------------------------------------------------------
// Fused per-step kernel: GEMM + GRU gate in one dispatch, no cross-block dep.
// grid (16, 8): x = h-tile (64 h each), y = group.
//   g=0: spk rows (M=128, b=tid). pass0: A[b,adr]@Whsi; pass1: A[b,spk]@Whs.
//   g=1: adr rows.                pass0: A[b,spk]@Whai; pass1: A[b,adr]@Wha.
//   g=2..7: others m-tile (128 of 768 rows). pass1 only: A[b,oth]@Who.
// Block owns cols {r,z,n} x 64 h with full K=1024 -> applies gate in regs,
// writes Anew (fp32) + AbfNew (bf16). Abf ping-pong avoids in-step races.
// acc[mf][cg][hf]: cg = 0:r (gi+gh), 1:z (gi+gh), 2:n_gi, 3:n_gh.
// ---------------------------------------------------------------------------
__global__ __launch_bounds__(256) void fused_step(
    const u16* __restrict__ AbfOld, u16* __restrict__ AbfNew,
    const float* __restrict__ Aold, float* __restrict__ Anew,
    const int* __restrict__ dig, int t, int tl, int Tc,
    const u16* __restrict__ Whsi, const u16* __restrict__ Whs,
    const u16* __restrict__ Whai, const u16* __restrict__ Wha,
    const u16* __restrict__ Who,
    const u16* __restrict__ GIX, const u16* __restrict__ GIA,
    const u16* __restrict__ GIO,
    const float* __restrict__ ws_bhh, const float* __restrict__ wa_bhh,
    const float* __restrict__ wo_bhh)
{
    __shared__ u16 As[128 * 32];
    __shared__ u16 Bs[192 * 32];
    __shared__ int r1off[128];   // pass0 A-gather rows (dual groups)
    __shared__ int r2off[128];   // pass1 A-gather rows == output rows
    __shared__ int gioff[128];   // GI row offsets
    const int tid = threadIdx.x;
    const int h0 = blockIdx.x * 64;
    const int g = blockIdx.y;
    const bool dual = (g < 2);

    const u16* W1 = (g == 0) ? Whsi : Whai;
    const u16* W2 = (g == 0) ? Whs : ((g == 1) ? Wha : Who);
    const u16* GIpre = (g == 0) ? GIX : ((g == 1) ? GIA : GIO);
    const float* bhh = (g == 0) ? ws_bhh : ((g == 1) ? wa_bhh : wo_bhh);

    if (tid < 128) {
        int b, role;
        if (dual) {
            b = tid;
            int spk = dig[(b * T_ + t) * 2 + 0];
            int adr = dig[(b * T_ + t) * 2 + 1];
            role = (g == 0) ? spk : adr;
            int other = (g == 0) ? adr : spk;
            r1off[tid] = (b * R_ + other) * H_;
        } else {
            int mo = (g - 2) * 128 + tid;
            b = mo / 6;
            int j = mo - b * 6;
            int spk = dig[(b * T_ + t) * 2 + 0];
            int adr = dig[(b * T_ + t) * 2 + 1];
            int cc = 0; role = 0;
            for (int r = 0; r < R_; ++r) {
                if (r != spk && r != adr) {
                    if (cc == j) { role = r; break; }
                    ++cc;
                }
            }
            r1off[tid] = 0;
        }
        r2off[tid] = (b * R_ + role) * H_;
        gioff[tid] = (b * Tc + tl) * H3_;
    }
    __syncthreads();

    const int lane = tid & 63;
    const int wv = tid >> 6;
    const int wm = (wv & 1) * 64;        // wave m-offset
    const int wh = (wv >> 1) * 32;       // wave h-sub-offset within 64-slice
    const int fr = lane & 15;
    const int kq = (lane >> 4) * 8;
    const int wbase = wv * 512;          // wave LDS chunk base (elems)

    f32x4 acc[4][4][2] = {};             // [mfrag][colgroup][hfrag]

    for (int pass = 0; pass < 2; ++pass) {
        if (pass == 0 && !dual) continue;
        const u16* W = pass ? W2 : W1;
        const int* roff = pass ? r2off : r1off;
        const int cg_n = pass ? 3 : 2;   // n-gate acc slot for this pass

        for (int k0 = 0; k0 < H_; k0 += 32) {
            // stage As: 128 rows x 32 k (8 KB) = 512 chunks, 2/thread
#pragma unroll
            for (int p = 0; p < 2; ++p) {
                int c = p * 256 + tid;
                int row = c >> 2, kc = (c & 3) * 8;
                async_cp16(AbfOld + roff[row] + k0 + kc, &As[p * 2048 + wbase]);
            }
            // stage Bs: 3 gate groups x 64 weight rows x 32 k (12 KB), 3/thread
#pragma unroll
            for (int p = 0; p < 3; ++p) {
                int c = p * 256 + tid;
                int grp = c >> 8, rowg = (c & 255) >> 2, kc = (c & 3) * 8;
                async_cp16(W + (size_t)(grp * H_ + h0 + rowg) * H_ + k0 + kc,
                           &Bs[p * 2048 + wbase]);
            }
            __syncthreads();
            bf16x8 a[4], bf[3][2];
#pragma unroll
            for (int mf = 0; mf < 4; ++mf)
                a[mf] = *(const bf16x8*)&As[(wm + mf * 16 + fr) * 32 + kq];
#pragma unroll
            for (int cw = 0; cw < 3; ++cw)
#pragma unroll
                for (int hf = 0; hf < 2; ++hf)
                    bf[cw][hf] = *(const bf16x8*)&Bs[(cw * 64 + wh + hf * 16 + fr) * 32 + kq];
#pragma unroll
            for (int mf = 0; mf < 4; ++mf)
#pragma unroll
                for (int cw = 0; cw < 3; ++cw) {
                    int cg = (cw == 2) ? cg_n : cw;
#pragma unroll
                    for (int hf = 0; hf < 2; ++hf)
                        acc[mf][cg][hf] = __builtin_amdgcn_mfma_f32_16x16x32_bf16(
                            a[mf], bf[cw][hf], acc[mf][cg][hf], 0, 0, 0);
                }
            __syncthreads();
        }
    }

    // ---- gate phase: all operands in registers / small loads ----
#pragma unroll
    for (int hf = 0; hf < 2; ++hf) {
        int h = h0 + wh + hf * 16 + fr;
        float bh_r = bhh[h];
        float bh_z = bhh[H_ + h];
        float bh_n = bhh[2 * H_ + h];
#pragma unroll
        for (int mf = 0; mf < 4; ++mf) {
#pragma unroll
            for (int i = 0; i < 4; ++i) {
                int row = wm + mf * 16 + (lane >> 4) * 4 + i;
                int gio = gioff[row];
                float gi_r = bf2f(GIpre[gio + h]);
                float gi_z = bf2f(GIpre[gio + H_ + h]);
                float gi_n = bf2f(GIpre[gio + 2 * H_ + h]);
                float rg = 1.0f / (1.0f + __expf(-(gi_r + acc[mf][0][hf][i] + bh_r)));
                float zg = 1.0f / (1.0f + __expf(-(gi_z + acc[mf][1][hf][i] + bh_z)));
                float ng = tanhf(gi_n + acc[mf][2][hf][i]
                                 + rg * (acc[mf][3][hf][i] + bh_n));
                size_t o = (size_t)r2off[row] + h;
                float hold = Aold[o];
                float out = (1.0f - zg) * ng + zg * hold;
                Anew[o] = out;
                AbfNew[o] = f2bf(out);
            }
        }
    }
}

// ---------------------------------------------------------------------------
extern "C" void kernel_launch(void* const* d_in, const int* in_sizes, int n_in,
                              void* d_out, int out_size, void* d_ws, size_t ws_size,
                              hipStream_t stream) {
    const float* enc    = (const float*)d_in[0];
    const int*   dig    = (const int*)d_in[1];
    const float* ws_ih  = (const float*)d_in[2];
    const float* ws_hh  = (const float*)d_in[3];
    const float* ws_bih = (const float*)d_in[4];
    const float* ws_bhh = (const float*)d_in[5];
    const float* wa_ih  = (const float*)d_in[6];
    const float* wa_hh  = (const float*)d_in[7];
    const float* wa_bih = (const float*)d_in[8];
    const float* wa_bhh = (const float*)d_in[9];
    const float* wo_ih  = (const float*)d_in[10];
    const float* wo_hh  = (const float*)d_in[11];
    const float* wo_bih = (const float*)d_in[12];
    const float* wo_bhh = (const float*)d_in[13];

    float* A0 = (float*)d_out;                    // (B, R, H) final output

    // ---- workspace layout (bytes) ----
    char* p = (char*)d_ws;
    auto take = [&](size_t bytes) { char* q = p; p += (bytes + 255) & ~(size_t)255; return q; };
    u16*   enc_bf = (u16*)  take((size_t)B_ * T_ * E_ * 2);          // 33.6 MB
    u16*   W1s    = (u16*)  take((size_t)H3_ * E_ * 2);              // 12.6 MB
    u16*   W1a    = (u16*)  take((size_t)H3_ * E_ * 2);
    u16*   W1o    = (u16*)  take((size_t)H3_ * E_ * 2);
    u16*   Whsi   = (u16*)  take((size_t)H3_ * H_ * 2);              // 6.3 MB
    u16*   Whai   = (u16*)  take((size_t)H3_ * H_ * 2);
    u16*   Whs    = (u16*)  take((size_t)H3_ * H_ * 2);
    u16*   Wha    = (u16*)  take((size_t)H3_ * H_ * 2);
    u16*   Who    = (u16*)  take((size_t)H3_ * H_ * 2);
    u16*   Abf0   = (u16*)  take((size_t)B_ * R_ * H_ * 2);          // 2 MB
    u16*   Abf1   = (u16*)  take((size_t)B_ * R_ * H_ * 2);          // 2 MB
    float* A1     = (float*)take((size_t)B_ * R_ * H_ * 4);          // 4 MB
    size_t fixed = (size_t)(p - (char*)d_ws);

    // chunk size: largest power-of-two Tc <= 64 fitting GI (3 sets, bf16)
    const size_t per_t = (size_t)3 * B_ * H3_ * 2;                   // 2.36 MB/step
    int Tc = 64;
    while (Tc > 1 && fixed + per_t * (size_t)Tc > ws_size) Tc >>= 1;
    int tcshift = 0;
    while ((1 << tcshift) < Tc) ++tcshift;
    const size_t GI_elems = (size_t)B_ * Tc * H3_;
    u16* GIX = (u16*)take(GI_elems * 2);
    u16* GIA = (u16*)take(GI_elems * 2);
    u16* GIO = (u16*)take(GI_elems * 2);

    dim3 blk(256);
    const size_t A_sz = (size_t)B_ * R_ * H_;

    // zero fp32 state (d_out) and bf16 state copy
    zero_kernel<<<dim3((int)((A_sz + 255) / 256)), blk, 0, stream>>>(A0, (int)A_sz);
    zero_kernel<<<dim3((int)((A_sz / 2 + 255) / 256)), blk, 0, stream>>>((float*)Abf0, (int)(A_sz / 2));

    // ---- one-time bf16 conversions ----
    {
        int t4;
        t4 = B_ * T_ * E_ / 4;
        conv_bf<<<dim3((t4 + 255) / 256), blk, 0, stream>>>(enc, E_, 0, E_, enc_bf, t4);
        t4 = H3_ * E_ / 4;
        conv_bf<<<dim3((t4 + 255) / 256), blk, 0, stream>>>(ws_ih, E_ + H_, 0, E_, W1s, t4);
        conv_bf<<<dim3((t4 + 255) / 256), blk, 0, stream>>>(wa_ih, E_ + H_, 0, E_, W1a, t4);
        conv_bf<<<dim3((t4 + 255) / 256), blk, 0, stream>>>(wo_ih, E_, 0, E_, W1o, t4);
        t4 = H3_ * H_ / 4;
        conv_bf<<<dim3((t4 + 255) / 256), blk, 0, stream>>>(ws_ih, E_ + H_, E_, H_, Whsi, t4);
        conv_bf<<<dim3((t4 + 255) / 256), blk, 0, stream>>>(wa_ih, E_ + H_, E_, H_, Whai, t4);
        conv_bf<<<dim3((t4 + 255) / 256), blk, 0, stream>>>(ws_hh, H_, 0, H_, Whs, t4);
        conv_bf<<<dim3((t4 + 255) / 256), blk, 0, stream>>>(wa_hh, H_, 0, H_, Wha, t4);
        conv_bf<<<dim3((t4 + 255) / 256), blk, 0, stream>>>(wo_hh, H_, 0, H_, Who, t4);
    }

    float* Acur = A0;   // fp32 master state (read)
    float* Anxt = A1;
    u16*   Bcur = Abf0; // bf16 state (read)
    u16*   Bnxt = Abf1;
    for (int t0 = 0; t0 < T_; t0 += Tc) {
        // Phase 1 (chunk): input-side gate contributions, bf16 MFMA.
        dim3 g1(H3_ / 128, (B_ * Tc) / 128);
        mfma_p1<<<g1, blk, 0, stream>>>(enc_bf, t0, tcshift, W1s, ws_bih, GIX);
        mfma_p1<<<g1, blk, 0, stream>>>(enc_bf, t0, tcshift, W1a, wa_bih, GIA);
        mfma_p1<<<g1, blk, 0, stream>>>(enc_bf, t0, tcshift, W1o, wo_bih, GIO);

        // Phase 2: one fused dispatch per timestep.
        for (int t = t0; t < t0 + Tc; ++t) {
            fused_step<<<dim3(16, 8), blk, 0, stream>>>(
                Bcur, Bnxt, Acur, Anxt, dig, t, t - t0, Tc,
                Whsi, Whs, Whai, Wha, Who, GIX, GIA, GIO,
                ws_bhh, wa_bhh, wo_bhh);
            float* tf = Acur; Acur = Anxt; Anxt = tf;
            u16*   tb = Bcur; Bcur = Bnxt; Bnxt = tb;
        }
    }
    // 64 steps (even number of swaps): final fp32 state is in A0 == d_out.
}